// Round 9
// baseline (653.970 us; speedup 1.0000x reference)
//
#include <hip/hip_runtime.h>
#include <stdint.h>

#define N_USERS 100000
#define N_ITEMS 50000
#define NTOT    150000
#define DIM     64
#define NNZ     2000000
#define NHOPS   3
#define NBLK_SCAN ((NTOT + 255) / 256)   // 587
#define NOCT    8
#define OCT_ROWS (NTOT / NOCT)           // 18750
#define OCT_CAP 230400                   // >= mean 218750 + 26 sigma, mult of 256
#define BPO 256                          // blocks per octant in k_scatter2

// ---------------- Threefry-2x32, 20 rounds (JAX-compatible) ----------------
__host__ __device__ inline void tf2x32(uint32_t k0, uint32_t k1,
                                       uint32_t x0, uint32_t x1,
                                       uint32_t& o0, uint32_t& o1) {
  uint32_t ks2 = k0 ^ k1 ^ 0x1BD11BDAu;
  x0 += k0; x1 += k1;
#define ROTL(x,r) (((x) << (r)) | ((x) >> (32 - (r))))
#define RND(r) { x0 += x1; x1 = ROTL(x1, r); x1 ^= x0; }
  RND(13) RND(15) RND(26) RND(6)
  x0 += k1;  x1 += ks2 + 1u;
  RND(17) RND(29) RND(16) RND(24)
  x0 += ks2; x1 += k0 + 2u;
  RND(13) RND(15) RND(26) RND(6)
  x0 += k0;  x1 += k1 + 3u;
  RND(17) RND(29) RND(16) RND(24)
  x0 += k1;  x1 += ks2 + 4u;
  RND(13) RND(15) RND(26) RND(6)
  x0 += ks2; x1 += k0 + 5u;
  o0 = x0; o1 = x1;
#undef RND
#undef ROTL
}

__device__ inline float tf_uniform(uint32_t k0, uint32_t k1, uint32_t idx) {
  uint32_t b1, b2;
  tf2x32(k0, k1, 0u, idx, b1, b2);
  uint32_t bits = b1 ^ b2;
  return __uint_as_float((bits >> 9) | 0x3f800000u) - 1.0f;
}

__device__ inline uint32_t keep_bits(uint32_t e,
                                     uint32_t e00, uint32_t e01,
                                     uint32_t e10, uint32_t e11,
                                     uint32_t e20, uint32_t e21) {
  uint32_t kb = 0u;                              // match reference fp exactly
  if (0.5f + tf_uniform(e00, e01, e) >= 1.0f) kb |= 1u;
  if (0.5f + tf_uniform(e10, e11, e) >= 1.0f) kb |= 2u;
  if (0.5f + tf_uniform(e20, e21, e) >= 1.0f) kb |= 4u;
  return kb;
}

// ---------------- kernels ----------------
// out layout: [n][hop(0..3)][d] float32. Row stride = 256 floats.

// hop0 = concat(user,item). Hop slices 1..3 are fully written by k_spmm_seg.
__global__ __launch_bounds__(256) void k_init(const float4* __restrict__ user,
                                              const float4* __restrict__ item,
                                              float4* __restrict__ out) {
  int idx = blockIdx.x * 256 + threadIdx.x;      // over NTOT*16 float4s
  if (idx >= NTOT * 16) return;
  int n = idx >> 4;
  float4 v = (n < N_USERS) ? user[idx] : item[idx - N_USERS * 16];
  out[(size_t)n * 64 + (idx & 15)] = v;
}

// Fused RNG + histogram + octant binning. 1 edge/thread, ballot-ranked
// coalesced writes into per-octant staging. gcur padded to 64B/counter.
__global__ __launch_bounds__(256) void k_hist_bin(const int* __restrict__ rows,
                                                  const int* __restrict__ cols,
                                                  const float* __restrict__ vals,
                                                  uint32_t* __restrict__ cnt,
                                                  uint32_t* __restrict__ gcur,
                                                  uint4* __restrict__ staging,
                                                  uint32_t e00, uint32_t e01,
                                                  uint32_t e10, uint32_t e11,
                                                  uint32_t e20, uint32_t e21) {
  __shared__ uint32_t wcnt[4][NOCT], wbase[4][NOCT];
  int t = threadIdx.x;
  int wave = t >> 6, lane = t & 63;
  int e = blockIdx.x * 256 + t;
  bool valid = (e < NNZ);
  uint32_t kb = valid ? keep_bits((uint32_t)e, e00, e01, e10, e11, e20, e21) : 0u;
  bool keep = (kb != 0u);
  int row = 0, col = 0; float v2 = 0.f; uint32_t oct = 0;
  if (keep) {
    row = rows[e]; col = cols[e]; v2 = vals[e] * 2.0f;   // 1/(1-0.5) = 2
    oct = (uint32_t)row / OCT_ROWS;
  }
  // per-wave per-bin masks via ballot; my rank within (wave, oct)
  uint64_t mymask = 0ull;
  uint32_t wc = 0u;
#pragma unroll
  for (int b = 0; b < NOCT; ++b) {
    uint64_t m = __ballot(keep && (oct == (uint32_t)b));
    if (lane == b) wc = (uint32_t)__popcll(m);
    if (keep && oct == (uint32_t)b) mymask = m;
  }
  if (lane < NOCT) wcnt[wave][lane] = wc;
  uint32_t rank = (uint32_t)__popcll(mymask & ((1ull << lane) - 1ull));
  __syncthreads();
  if (t < NOCT) {                    // thread t handles bin t
    uint32_t c0 = wcnt[0][t], c1 = wcnt[1][t], c2 = wcnt[2][t], c3 = wcnt[3][t];
    uint32_t tot = c0 + c1 + c2 + c3;
    uint32_t base = tot ? atomicAdd(&gcur[t * 16], tot) : 0u;
    wbase[0][t] = base;
    wbase[1][t] = base + c0;
    wbase[2][t] = base + c0 + c1;
    wbase[3][t] = base + c0 + c1 + c2;
  }
  __syncthreads();
  if (keep) {
    atomicAdd(&cnt[row], 1u);
    uint32_t dst = wbase[wave][oct] + rank;
    staging[(size_t)oct * OCT_CAP + dst] =
        make_uint4((uint32_t)row, ((uint32_t)col << 3) | kb,
                   __float_as_uint(v2), 0u);
  }
}

// block-level exclusive scan (256-wide) + block totals
__global__ __launch_bounds__(256) void k_scan1(const uint32_t* __restrict__ cnt,
                                               uint32_t* __restrict__ strt,
                                               uint32_t* __restrict__ part) {
  __shared__ uint32_t s[256];
  int t = threadIdx.x;
  int i = blockIdx.x * 256 + t;
  uint32_t x = (i < NTOT) ? cnt[i] : 0u;
  s[t] = x; __syncthreads();
  for (int off = 1; off < 256; off <<= 1) {
    uint32_t y = (t >= off) ? s[t - off] : 0u;
    __syncthreads();
    s[t] += y;
    __syncthreads();
  }
  if (i < NTOT) strt[i] = s[t] - x;              // exclusive
  if (t == 255) part[blockIdx.x] = s[255];       // block total
}

// exclusive scan of the 587 block totals (single block)
__global__ __launch_bounds__(1024) void k_scan2(uint32_t* __restrict__ part) {
  __shared__ uint32_t s[1024];
  int t = threadIdx.x;
  uint32_t x = (t < NBLK_SCAN) ? part[t] : 0u;
  s[t] = x; __syncthreads();
  for (int off = 1; off < 1024; off <<= 1) {
    uint32_t y = (t >= off) ? s[t - off] : 0u;
    __syncthreads();
    s[t] += y;
    __syncthreads();
  }
  if (t < NBLK_SCAN) part[t] = s[t] - x;         // exclusive
}

// add block offsets; init per-row scatter cursors
__global__ __launch_bounds__(256) void k_scan3(uint32_t* __restrict__ strt,
                                               const uint32_t* __restrict__ part,
                                               uint32_t* __restrict__ cur) {
  int i = blockIdx.x * 256 + threadIdx.x;
  if (i >= NTOT) return;
  uint32_t v = strt[i] + part[i >> 8];
  strt[i] = v;
  cur[i] = v;
}

// XCD-affine re-scatter: octant o's staging (sequential) -> row-sorted rec
// window (1.75 MB). Streaming footprint << 4 MB L2 -> full-line writebacks.
__global__ __launch_bounds__(256) void k_scatter2(const uint4* __restrict__ staging,
                                                  const uint32_t* __restrict__ gcur,
                                                  uint32_t* __restrict__ cur,
                                                  uint2* __restrict__ rec) {
  uint32_t oct = (uint32_t)(blockIdx.x & 7);     // presumed XCD (round-robin)
  uint32_t slot = (uint32_t)(blockIdx.x >> 3);
  uint32_t n = gcur[oct * 16];
  const uint4* sg = staging + (size_t)oct * OCT_CAP;
  for (uint32_t i = slot * 256 + threadIdx.x; i < n; i += BPO * 256) {
    uint4 v = sg[i];
    uint32_t j = atomicAdd(&cur[v.x], 1u);
    rec[j] = make_uint2(v.y, v.z);
  }
}

// ---- fallback (small ws): round-7 style hist + single-pass scatter ----
__global__ __launch_bounds__(256) void k_hist_fb(const int* __restrict__ rows,
                                                 uint32_t* __restrict__ cnt,
                                                 uint8_t* __restrict__ kbits,
                                                 uint32_t e00, uint32_t e01,
                                                 uint32_t e10, uint32_t e11,
                                                 uint32_t e20, uint32_t e21) {
  int e = blockIdx.x * 256 + threadIdx.x;
  if (e >= NNZ) return;
  uint32_t kb = keep_bits((uint32_t)e, e00, e01, e10, e11, e20, e21);
  int row = rows[e];
  uint32_t oct = (uint32_t)row / OCT_ROWS;
  kbits[e] = (uint8_t)(kb | (oct << 4));
  if (kb) atomicAdd(&cnt[row], 1u);
}

__global__ __launch_bounds__(256) void k_scatter_fb(const float* __restrict__ vals,
                                                    const int* __restrict__ rows,
                                                    const int* __restrict__ cols,
                                                    const uint8_t* __restrict__ kbits,
                                                    uint32_t* __restrict__ cur,
                                                    uint2* __restrict__ rec) {
  int e = (blockIdx.x >> 3) * 256 + threadIdx.x;
  if (e >= NNZ) return;
  uint32_t oct = (uint32_t)(blockIdx.x & 7);
  uint32_t kbv = kbits[e];
  if ((kbv >> 4) != oct) return;
  uint32_t kb = kbv & 7u;
  if (!kb) return;
  uint32_t j = atomicAdd(&cur[rows[e]], 1u);
  rec[j] = make_uint2(((uint32_t)cols[e] << 3) | kb,
                      __float_as_uint(vals[e] * 2.0f));
}

// segmented SpMM: one WAVE per ROW. The row's edge list is split round-robin
// over 4 lane-groups (g = lane>>4) -> zero loop-count divergence; each group
// gathers 16 lanes x float4 = the full 256B source slice. Masked-this-hop
// edges SKIP their gather. Unroll-2/group = 8 gathers in flight per wave.
// Cross-group __shfl_xor reduce, fused message dropout, g==0 stores.
__global__ __launch_bounds__(256) void k_spmm_seg(const uint32_t* __restrict__ strt,
                                                  const uint32_t* __restrict__ cnt,
                                                  const uint2* __restrict__ rec,
                                                  float* __restrict__ out,
                                                  int hop, uint32_t km0, uint32_t km1) {
  int row = (blockIdx.x * 256 + threadIdx.x) >> 6;
  if (row >= NTOT) return;
  int lane = threadIdx.x & 63;
  int g = lane >> 4;                 // edge subgroup 0..3
  int q = lane & 15;                 // float4 chunk 0..15
  uint32_t s = strt[row];
  uint32_t e = s + cnt[row];
  const uint32_t mask = 1u << hop;
  // src row c, float4 chunk q lives at float4 index c*64 + hop*16 + q
  const float4* srcb = (const float4*)out + (size_t)hop * 16 + q;
  float4 aA = {0.f, 0.f, 0.f, 0.f}, aB = aA;
  uint32_t j = s + (uint32_t)g;
  for (; j + 4 < e; j += 8) {
    uint2 rA = rec[j];
    uint2 rB = rec[j + 4];
    if (rA.x & mask) {
      float v = __uint_as_float(rA.y);
      float4 sv = srcb[(size_t)(rA.x >> 3) * 64];
      aA.x += v * sv.x; aA.y += v * sv.y; aA.z += v * sv.z; aA.w += v * sv.w;
    }
    if (rB.x & mask) {
      float v = __uint_as_float(rB.y);
      float4 sv = srcb[(size_t)(rB.x >> 3) * 64];
      aB.x += v * sv.x; aB.y += v * sv.y; aB.z += v * sv.z; aB.w += v * sv.w;
    }
  }
  if (j < e) {
    uint2 r = rec[j];
    if (r.x & mask) {
      float v = __uint_as_float(r.y);
      float4 sv = srcb[(size_t)(r.x >> 3) * 64];
      aA.x += v * sv.x; aA.y += v * sv.y; aA.z += v * sv.z; aA.w += v * sv.w;
    }
  }
  float4 a;
  a.x = aA.x + aB.x; a.y = aA.y + aB.y; a.z = aA.z + aB.z; a.w = aA.w + aB.w;
  // reduce the 4 groups (same q, different g): lanes differ in bits 4,5
  a.x += __shfl_xor(a.x, 16); a.y += __shfl_xor(a.y, 16);
  a.z += __shfl_xor(a.z, 16); a.w += __shfl_xor(a.w, 16);
  a.x += __shfl_xor(a.x, 32); a.y += __shfl_xor(a.y, 32);
  a.z += __shfl_xor(a.z, 32); a.w += __shfl_xor(a.w, 32);
  if (g == 0) {
    // message dropout (inverted, keep iff u < 0.9), flat over (NTOT, DIM)
    uint32_t base = (uint32_t)(row * 64 + q * 4);
    float u0 = tf_uniform(km0, km1, base + 0u);
    float u1 = tf_uniform(km0, km1, base + 1u);
    float u2 = tf_uniform(km0, km1, base + 2u);
    float u3 = tf_uniform(km0, km1, base + 3u);
    const float sc = (float)(1.0 / 0.9);
    a.x = (u0 < 0.9f) ? a.x * sc : 0.0f;
    a.y = (u1 < 0.9f) ? a.y * sc : 0.0f;
    a.z = (u2 < 0.9f) ? a.z * sc : 0.0f;
    a.w = (u3 < 0.9f) ? a.w * sc : 0.0f;
    *(float4*)(out + ((size_t)row * 4 + hop + 1) * 64 + q * 4) = a;
  }
}

// ---------------- launch ----------------
extern "C" void kernel_launch(void* const* d_in, const int* in_sizes, int n_in,
                              void* d_out, int out_size, void* d_ws, size_t ws_size,
                              hipStream_t stream) {
  const float* user = (const float*)d_in[0];
  const float* item = (const float*)d_in[1];
  const float* vals = (const float*)d_in[2];
  const int*   rows = (const int*)d_in[3];
  const int*   cols = (const int*)d_in[4];
  float* out = (float*)d_out;

  // workspace layout (big path ~47.3 MB; fallback ~19.6 MB)
  char* w = (char*)d_ws;
  uint32_t* cnt     = (uint32_t*)(w);                 // 600,000 B
  uint32_t* gcur    = (uint32_t*)(w + 600000);        // 512 B (8 x 64B-padded)
  uint32_t* strt    = (uint32_t*)(w + 600512);        // 600,000 B
  uint32_t* cur     = (uint32_t*)(w + 1200512);       // 600,000 B
  uint32_t* part    = (uint32_t*)(w + 1800512);       // 4,096 B
  uint2*    rec     = (uint2*)   (w + 1804608);       // 16,000,000 B
  uint4*    staging = (uint4*)   (w + 17804608);      // 29,491,200 B
  uint8_t*  kbits   = (uint8_t*) (w + 17804608);      // fallback: 2 MB
  const size_t NEEDED = 17804608 + (size_t)NOCT * OCT_CAP * 16;
  bool big = ws_size >= NEEDED;

  // host-side key schedule: key(42) -> per-hop (dkey, ke, km)
  uint32_t k0 = 0u, k1 = 42u;
  uint32_t ke[NHOPS][2], km[NHOPS][2];
  for (int h = 0; h < NHOPS; ++h) {
    uint32_t nk0, nk1;
    tf2x32(k0, k1, 0u, 0u, nk0, nk1);
    tf2x32(k0, k1, 0u, 1u, ke[h][0], ke[h][1]);
    tf2x32(k0, k1, 0u, 2u, km[h][0], km[h][1]);
    k0 = nk0; k1 = nk1;
  }

  hipMemsetAsync(cnt, 0, 600512, stream);   // cnt + gcur
  if (big) {
    k_hist_bin<<<(NNZ + 255) / 256, 256, 0, stream>>>(
        rows, cols, vals, cnt, gcur, staging,
        ke[0][0], ke[0][1], ke[1][0], ke[1][1], ke[2][0], ke[2][1]);
  } else {
    k_hist_fb<<<(NNZ + 255) / 256, 256, 0, stream>>>(
        rows, cnt, kbits,
        ke[0][0], ke[0][1], ke[1][0], ke[1][1], ke[2][0], ke[2][1]);
  }
  k_scan1<<<NBLK_SCAN, 256, 0, stream>>>(cnt, strt, part);
  k_scan2<<<1, 1024, 0, stream>>>(part);
  k_scan3<<<NBLK_SCAN, 256, 0, stream>>>(strt, part, cur);
  if (big) {
    k_scatter2<<<NOCT * BPO, 256, 0, stream>>>(staging, gcur, cur, rec);
  } else {
    k_scatter_fb<<<NOCT * ((NNZ + 255) / 256), 256, 0, stream>>>(
        vals, rows, cols, kbits, cur, rec);
  }
  k_init<<<(NTOT * 16 + 255) / 256, 256, 0, stream>>>(
      (const float4*)user, (const float4*)item, (float4*)out);

  for (int h = 0; h < NHOPS; ++h) {
    k_spmm_seg<<<(NTOT * 64) / 256, 256, 0, stream>>>(
        strt, cnt, rec, out, h, km[h][0], km[h][1]);
  }
}

// Round 10
// 351.192 us; speedup vs baseline: 1.8621x; 1.8621x over previous
//
#include <hip/hip_runtime.h>
#include <stdint.h>

#define N_USERS 100000
#define N_ITEMS 50000
#define NTOT    150000
#define DIM     64
#define NNZ     2000000
#define NHOPS   3
#define NBLK_SCAN ((NTOT + 255) / 256)   // 587
#define NOCT    8
#define OCT_ROWS (NTOT / NOCT)           // 18750
#define NALIAS  8
#define ALIAS_CAP 28800                  // expected 27.3K + ~9 sigma
#define OCT_CAP (NALIAS * ALIAS_CAP)     // 230400 (same 29.49MB staging)
#define HB_ITERS 8                       // 2048 edges/block
#define BPO 256                          // scatter2 blocks per octant

// ---------------- Threefry-2x32, 20 rounds (JAX-compatible) ----------------
__host__ __device__ inline void tf2x32(uint32_t k0, uint32_t k1,
                                       uint32_t x0, uint32_t x1,
                                       uint32_t& o0, uint32_t& o1) {
  uint32_t ks2 = k0 ^ k1 ^ 0x1BD11BDAu;
  x0 += k0; x1 += k1;
#define ROTL(x,r) (((x) << (r)) | ((x) >> (32 - (r))))
#define RND(r) { x0 += x1; x1 = ROTL(x1, r); x1 ^= x0; }
  RND(13) RND(15) RND(26) RND(6)
  x0 += k1;  x1 += ks2 + 1u;
  RND(17) RND(29) RND(16) RND(24)
  x0 += ks2; x1 += k0 + 2u;
  RND(13) RND(15) RND(26) RND(6)
  x0 += k0;  x1 += k1 + 3u;
  RND(17) RND(29) RND(16) RND(24)
  x0 += k1;  x1 += ks2 + 4u;
  RND(13) RND(15) RND(26) RND(6)
  x0 += ks2; x1 += k0 + 5u;
  o0 = x0; o1 = x1;
#undef RND
#undef ROTL
}

__device__ inline float tf_uniform(uint32_t k0, uint32_t k1, uint32_t idx) {
  uint32_t b1, b2;
  tf2x32(k0, k1, 0u, idx, b1, b2);
  uint32_t bits = b1 ^ b2;
  return __uint_as_float((bits >> 9) | 0x3f800000u) - 1.0f;
}

__device__ inline uint32_t keep_bits(uint32_t e,
                                     uint32_t e00, uint32_t e01,
                                     uint32_t e10, uint32_t e11,
                                     uint32_t e20, uint32_t e21) {
  uint32_t kb = 0u;                              // match reference fp exactly
  if (0.5f + tf_uniform(e00, e01, e) >= 1.0f) kb |= 1u;
  if (0.5f + tf_uniform(e10, e11, e) >= 1.0f) kb |= 2u;
  if (0.5f + tf_uniform(e20, e21, e) >= 1.0f) kb |= 4u;
  return kb;
}

// ---------------- kernels ----------------
// out layout: [n][hop(0..3)][d] float32. Row stride = 256 floats.

// hop0 = concat(user,item). Hop slices 1..3 are fully written by k_spmm_seg.
__global__ __launch_bounds__(256) void k_init(const float4* __restrict__ user,
                                              const float4* __restrict__ item,
                                              float4* __restrict__ out) {
  int idx = blockIdx.x * 256 + threadIdx.x;      // over NTOT*16 float4s
  if (idx >= NTOT * 16) return;
  int n = idx >> 4;
  float4 v = (n < N_USERS) ? user[idx] : item[idx - N_USERS * 16];
  out[(size_t)n * 64 + (idx & 15)] = v;
}

// Fused RNG + histogram + octant binning. 2048 edges/block in 8 register-
// stashed sub-iterations (ballot-ranked, zero LDS atomics, 2 barriers).
// ONE gcur reservation per octant per block, aliased 8-way -> ~122
// serialized atomics per counter line instead of 7813.
__global__ __launch_bounds__(256) void k_hist_bin(const int* __restrict__ rows,
                                                  const int* __restrict__ cols,
                                                  const float* __restrict__ vals,
                                                  uint32_t* __restrict__ cnt,
                                                  uint32_t* __restrict__ gcur,
                                                  uint4* __restrict__ staging,
                                                  uint32_t e00, uint32_t e01,
                                                  uint32_t e10, uint32_t e11,
                                                  uint32_t e20, uint32_t e21) {
  __shared__ uint32_t wcnt[HB_ITERS][4][NOCT];   // per (iter, wave, oct) count
  __shared__ uint32_t wbase[HB_ITERS][4][NOCT];  // write base per group
  int t = threadIdx.x;
  int wave = t >> 6, lane = t & 63;
  uint32_t alias = (uint32_t)(blockIdx.x & (NALIAS - 1));
  int ebase = blockIdx.x * (HB_ITERS * 256);

  uint32_t srow[HB_ITERS], scol[HB_ITERS], sval[HB_ITERS];
  uint32_t rankpack[2] = {0u, 0u};

#pragma unroll
  for (int it = 0; it < HB_ITERS; ++it) {
    int e = ebase + it * 256 + t;
    bool valid = (e < NNZ);
    uint32_t kb = valid ? keep_bits((uint32_t)e, e00, e01, e10, e11, e20, e21) : 0u;
    bool keep = (kb != 0u);
    uint32_t row = 0, colkb = 0, v2b = 0, oct = 0;
    if (keep) {
      row = (uint32_t)rows[e];
      colkb = ((uint32_t)cols[e] << 3) | kb;
      v2b = __float_as_uint(vals[e] * 2.0f);     // 1/(1-0.5) = 2
      oct = row / OCT_ROWS;
      atomicAdd(&cnt[row], 1u);
    }
    // per-wave per-bin ballot; my rank within (wave, oct)
    uint64_t mymask = 0ull;
    uint32_t wc = 0u;
#pragma unroll
    for (int b = 0; b < NOCT; ++b) {
      uint64_t m = __ballot(keep && (oct == (uint32_t)b));
      if (lane == b) wc = (uint32_t)__popcll(m);
      if (keep && oct == (uint32_t)b) mymask = m;
    }
    if (lane < NOCT) wcnt[it][wave][lane] = wc;
    uint32_t rank = (uint32_t)__popcll(mymask & ((1ull << lane) - 1ull));
    rankpack[it >> 2] |= rank << ((it & 3) * 8);
    srow[it] = row; scol[it] = colkb; sval[it] = v2b;
  }
  __syncthreads();
  if (t < NOCT) {                    // thread t owns octant t
    uint32_t tot = 0u;
#pragma unroll
    for (int it = 0; it < HB_ITERS; ++it)
      for (int w = 0; w < 4; ++w) tot += wcnt[it][w][t];
    uint32_t run = tot ? atomicAdd(&gcur[(t * NALIAS + alias) * 16], tot) : 0u;
#pragma unroll
    for (int it = 0; it < HB_ITERS; ++it)
      for (int w = 0; w < 4; ++w) {
        wbase[it][w][t] = run;
        run += wcnt[it][w][t];
      }
  }
  __syncthreads();
#pragma unroll
  for (int it = 0; it < HB_ITERS; ++it) {
    uint32_t colkb = scol[it];
    if (colkb & 7u) {
      uint32_t row = srow[it];
      uint32_t oct = row / OCT_ROWS;
      uint32_t rank = (rankpack[it >> 2] >> ((it & 3) * 8)) & 0xFFu;
      size_t dst = (size_t)oct * OCT_CAP + (size_t)alias * ALIAS_CAP
                 + wbase[it][wave][oct] + rank;
      staging[dst] = make_uint4(row, colkb, sval[it], 0u);
    }
  }
}

// block-level exclusive scan (256-wide) + block totals
__global__ __launch_bounds__(256) void k_scan1(const uint32_t* __restrict__ cnt,
                                               uint32_t* __restrict__ strt,
                                               uint32_t* __restrict__ part) {
  __shared__ uint32_t s[256];
  int t = threadIdx.x;
  int i = blockIdx.x * 256 + t;
  uint32_t x = (i < NTOT) ? cnt[i] : 0u;
  s[t] = x; __syncthreads();
  for (int off = 1; off < 256; off <<= 1) {
    uint32_t y = (t >= off) ? s[t - off] : 0u;
    __syncthreads();
    s[t] += y;
    __syncthreads();
  }
  if (i < NTOT) strt[i] = s[t] - x;              // exclusive
  if (t == 255) part[blockIdx.x] = s[255];       // block total
}

// exclusive scan of the 587 block totals (single block)
__global__ __launch_bounds__(1024) void k_scan2(uint32_t* __restrict__ part) {
  __shared__ uint32_t s[1024];
  int t = threadIdx.x;
  uint32_t x = (t < NBLK_SCAN) ? part[t] : 0u;
  s[t] = x; __syncthreads();
  for (int off = 1; off < 1024; off <<= 1) {
    uint32_t y = (t >= off) ? s[t - off] : 0u;
    __syncthreads();
    s[t] += y;
    __syncthreads();
  }
  if (t < NBLK_SCAN) part[t] = s[t] - x;         // exclusive
}

// add block offsets; init per-row scatter cursors
__global__ __launch_bounds__(256) void k_scan3(uint32_t* __restrict__ strt,
                                               const uint32_t* __restrict__ part,
                                               uint32_t* __restrict__ cur) {
  int i = blockIdx.x * 256 + threadIdx.x;
  if (i >= NTOT) return;
  uint32_t v = strt[i] + part[i >> 8];
  strt[i] = v;
  cur[i] = v;
}

// XCD-affine re-scatter: octant o's staging segments (sequential reads) ->
// row-sorted rec window (1.75 MB resident in that XCD's L2).
__global__ __launch_bounds__(256) void k_scatter2(const uint4* __restrict__ staging,
                                                  const uint32_t* __restrict__ gcur,
                                                  uint32_t* __restrict__ cur,
                                                  uint2* __restrict__ rec) {
  uint32_t oct = (uint32_t)(blockIdx.x & 7);     // presumed XCD (round-robin)
  uint32_t alias = (uint32_t)((blockIdx.x >> 3) & (NALIAS - 1));
  uint32_t slot = (uint32_t)(blockIdx.x >> 6);   // 0..31
  uint32_t n = gcur[(oct * NALIAS + alias) * 16];
  const uint4* sg = staging + (size_t)oct * OCT_CAP + (size_t)alias * ALIAS_CAP;
  for (uint32_t i = slot * 256 + threadIdx.x; i < n; i += (BPO / NALIAS) * 256) {
    uint4 v = sg[i];
    uint32_t j = atomicAdd(&cur[v.x], 1u);
    rec[j] = make_uint2(v.y, v.z);
  }
}

// ---- fallback (small ws): round-7 style hist + single-pass scatter ----
__global__ __launch_bounds__(256) void k_hist_fb(const int* __restrict__ rows,
                                                 uint32_t* __restrict__ cnt,
                                                 uint8_t* __restrict__ kbits,
                                                 uint32_t e00, uint32_t e01,
                                                 uint32_t e10, uint32_t e11,
                                                 uint32_t e20, uint32_t e21) {
  int e = blockIdx.x * 256 + threadIdx.x;
  if (e >= NNZ) return;
  uint32_t kb = keep_bits((uint32_t)e, e00, e01, e10, e11, e20, e21);
  int row = rows[e];
  uint32_t oct = (uint32_t)row / OCT_ROWS;
  kbits[e] = (uint8_t)(kb | (oct << 4));
  if (kb) atomicAdd(&cnt[row], 1u);
}

__global__ __launch_bounds__(256) void k_scatter_fb(const float* __restrict__ vals,
                                                    const int* __restrict__ rows,
                                                    const int* __restrict__ cols,
                                                    const uint8_t* __restrict__ kbits,
                                                    uint32_t* __restrict__ cur,
                                                    uint2* __restrict__ rec) {
  int e = (blockIdx.x >> 3) * 256 + threadIdx.x;
  if (e >= NNZ) return;
  uint32_t oct = (uint32_t)(blockIdx.x & 7);
  uint32_t kbv = kbits[e];
  if ((kbv >> 4) != oct) return;
  uint32_t kb = kbv & 7u;
  if (!kb) return;
  uint32_t j = atomicAdd(&cur[rows[e]], 1u);
  rec[j] = make_uint2(((uint32_t)cols[e] << 3) | kb,
                      __float_as_uint(vals[e] * 2.0f));
}

// segmented SpMM (round-6/7/8 proven version): one WAVE per 4 rows;
// 16 lanes x float4 per row; 4 independent row-chains x unroll-4 = up to
// 16 outstanding gathers/wave. Dropped-this-hop edges gather row 0 (L1-hot)
// with v=0 (branchless). rec loads cached. Fused message dropout.
__global__ __launch_bounds__(256) void k_spmm_seg(const uint32_t* __restrict__ strt,
                                                  const uint32_t* __restrict__ cnt,
                                                  const uint2* __restrict__ rec,
                                                  float* __restrict__ out,
                                                  int hop, uint32_t km0, uint32_t km1) {
  int wave = (blockIdx.x * 256 + threadIdx.x) >> 6;
  int lane = threadIdx.x & 63;
  int g = lane >> 4;                 // row subgroup 0..3
  int q = lane & 15;                 // float4 chunk 0..15
  int row = wave * 4 + g;
  if (row >= NTOT) return;
  uint32_t s = strt[row];
  uint32_t e = s + cnt[row];
  const uint32_t mask = 1u << hop;
  // src row c, float4 chunk q lives at float4 index c*64 + hop*16 + q
  const float4* srcb = (const float4*)out + (size_t)hop * 16 + q;
  float4 a0 = {0.f,0.f,0.f,0.f}, a1 = a0, a2 = a0, a3 = a0;
  uint32_t j = s;
  for (; j + 4 <= e; j += 4) {
    uint2 r0 = rec[j], r1 = rec[j + 1], r2 = rec[j + 2], r3 = rec[j + 3];
    bool k0 = (r0.x & mask) != 0u, k1 = (r1.x & mask) != 0u;
    bool k2 = (r2.x & mask) != 0u, k3 = (r3.x & mask) != 0u;
    size_t c0 = k0 ? (size_t)(r0.x >> 3) * 64 : 0;
    size_t c1 = k1 ? (size_t)(r1.x >> 3) * 64 : 0;
    size_t c2 = k2 ? (size_t)(r2.x >> 3) * 64 : 0;
    size_t c3 = k3 ? (size_t)(r3.x >> 3) * 64 : 0;
    float4 s0 = srcb[c0], s1 = srcb[c1], s2 = srcb[c2], s3 = srcb[c3];
    float v0 = k0 ? __uint_as_float(r0.y) : 0.f;
    float v1 = k1 ? __uint_as_float(r1.y) : 0.f;
    float v2 = k2 ? __uint_as_float(r2.y) : 0.f;
    float v3 = k3 ? __uint_as_float(r3.y) : 0.f;
    a0.x += v0 * s0.x; a0.y += v0 * s0.y; a0.z += v0 * s0.z; a0.w += v0 * s0.w;
    a1.x += v1 * s1.x; a1.y += v1 * s1.y; a1.z += v1 * s1.z; a1.w += v1 * s1.w;
    a2.x += v2 * s2.x; a2.y += v2 * s2.y; a2.z += v2 * s2.z; a2.w += v2 * s2.w;
    a3.x += v3 * s3.x; a3.y += v3 * s3.y; a3.z += v3 * s3.z; a3.w += v3 * s3.w;
  }
  for (; j < e; ++j) {
    uint2 r = rec[j];
    if (r.x & mask) {
      float v = __uint_as_float(r.y);
      float4 sv = srcb[(size_t)(r.x >> 3) * 64];
      a0.x += v * sv.x; a0.y += v * sv.y; a0.z += v * sv.z; a0.w += v * sv.w;
    }
  }
  float4 acc;
  acc.x = (a0.x + a1.x) + (a2.x + a3.x);
  acc.y = (a0.y + a1.y) + (a2.y + a3.y);
  acc.z = (a0.z + a1.z) + (a2.z + a3.z);
  acc.w = (a0.w + a1.w) + (a2.w + a3.w);
  // message dropout (inverted, keep iff u < 0.9), flat index over (NTOT, DIM)
  uint32_t base = (uint32_t)(row * 64 + q * 4);
  float u0 = tf_uniform(km0, km1, base + 0u);
  float u1 = tf_uniform(km0, km1, base + 1u);
  float u2 = tf_uniform(km0, km1, base + 2u);
  float u3 = tf_uniform(km0, km1, base + 3u);
  const float sc = (float)(1.0 / 0.9);
  acc.x = (u0 < 0.9f) ? acc.x * sc : 0.0f;
  acc.y = (u1 < 0.9f) ? acc.y * sc : 0.0f;
  acc.z = (u2 < 0.9f) ? acc.z * sc : 0.0f;
  acc.w = (u3 < 0.9f) ? acc.w * sc : 0.0f;
  ((float4*)(out + ((size_t)row * 4 + hop + 1) * 64))[q] = acc;
}

// ---------------- launch ----------------
extern "C" void kernel_launch(void* const* d_in, const int* in_sizes, int n_in,
                              void* d_out, int out_size, void* d_ws, size_t ws_size,
                              hipStream_t stream) {
  const float* user = (const float*)d_in[0];
  const float* item = (const float*)d_in[1];
  const float* vals = (const float*)d_in[2];
  const int*   rows = (const int*)d_in[3];
  const int*   cols = (const int*)d_in[4];
  float* out = (float*)d_out;

  // workspace layout (big path ~47.3 MB; fallback ~19.8 MB)
  char* w = (char*)d_ws;
  uint32_t* cnt     = (uint32_t*)(w);                 // 600,000 B
  uint32_t* gcur    = (uint32_t*)(w + 600000);        // 4,096 B (64 x 64B)
  uint32_t* strt    = (uint32_t*)(w + 604096);        // 600,000 B
  uint32_t* cur     = (uint32_t*)(w + 1204096);       // 600,000 B
  uint32_t* part    = (uint32_t*)(w + 1804096);       // 4,096 B
  uint2*    rec     = (uint2*)   (w + 1808192);       // 16,000,000 B
  uint4*    staging = (uint4*)   (w + 17808192);      // 29,491,200 B
  uint8_t*  kbits   = (uint8_t*) (w + 17808192);      // fallback: 2 MB
  const size_t NEEDED = 17808192 + (size_t)NOCT * OCT_CAP * 16;
  bool big = ws_size >= NEEDED;

  // host-side key schedule: key(42) -> per-hop (dkey, ke, km)
  uint32_t k0 = 0u, k1 = 42u;
  uint32_t ke[NHOPS][2], km[NHOPS][2];
  for (int h = 0; h < NHOPS; ++h) {
    uint32_t nk0, nk1;
    tf2x32(k0, k1, 0u, 0u, nk0, nk1);
    tf2x32(k0, k1, 0u, 1u, ke[h][0], ke[h][1]);
    tf2x32(k0, k1, 0u, 2u, km[h][0], km[h][1]);
    k0 = nk0; k1 = nk1;
  }

  hipMemsetAsync(cnt, 0, 604096, stream);   // cnt + gcur
  if (big) {
    k_hist_bin<<<(NNZ + HB_ITERS * 256 - 1) / (HB_ITERS * 256), 256, 0, stream>>>(
        rows, cols, vals, cnt, gcur, staging,
        ke[0][0], ke[0][1], ke[1][0], ke[1][1], ke[2][0], ke[2][1]);
  } else {
    k_hist_fb<<<(NNZ + 255) / 256, 256, 0, stream>>>(
        rows, cnt, kbits,
        ke[0][0], ke[0][1], ke[1][0], ke[1][1], ke[2][0], ke[2][1]);
  }
  k_scan1<<<NBLK_SCAN, 256, 0, stream>>>(cnt, strt, part);
  k_scan2<<<1, 1024, 0, stream>>>(part);
  k_scan3<<<NBLK_SCAN, 256, 0, stream>>>(strt, part, cur);
  if (big) {
    k_scatter2<<<NOCT * BPO, 256, 0, stream>>>(staging, gcur, cur, rec);
  } else {
    k_scatter_fb<<<NOCT * ((NNZ + 255) / 256), 256, 0, stream>>>(
        vals, rows, cols, kbits, cur, rec);
  }
  k_init<<<(NTOT * 16 + 255) / 256, 256, 0, stream>>>(
      (const float4*)user, (const float4*)item, (float4*)out);

  for (int h = 0; h < NHOPS; ++h) {
    k_spmm_seg<<<((NTOT + 3) / 4 * 64 + 255) / 256, 256, 0, stream>>>(
        strt, cnt, rec, out, h, km[h][0], km[h][1]);
  }
}

// Round 11
// 289.317 us; speedup vs baseline: 2.2604x; 1.2139x over previous
//
#include <hip/hip_runtime.h>
#include <stdint.h>

#define N_USERS 100000
#define N_ITEMS 50000
#define NTOT    150000
#define DIM     64
#define NNZ     2000000
#define NHOPS   3
#define NBLK_SCAN ((NTOT + 255) / 256)   // 587
#define NOCT    8
#define OCT_ROWS (NTOT / NOCT)           // 18750 (fallback path)
#define NBUCK   293                      // buckets of 512 rows (row>>9)
#define BCAP    6400                     // mean 5973 + ~5.5 sigma
#define HB_ITERS 8                       // 2048 edges per hist block

// ---------------- Threefry-2x32, 20 rounds (JAX-compatible) ----------------
__host__ __device__ inline void tf2x32(uint32_t k0, uint32_t k1,
                                       uint32_t x0, uint32_t x1,
                                       uint32_t& o0, uint32_t& o1) {
  uint32_t ks2 = k0 ^ k1 ^ 0x1BD11BDAu;
  x0 += k0; x1 += k1;
#define ROTL(x,r) (((x) << (r)) | ((x) >> (32 - (r))))
#define RND(r) { x0 += x1; x1 = ROTL(x1, r); x1 ^= x0; }
  RND(13) RND(15) RND(26) RND(6)
  x0 += k1;  x1 += ks2 + 1u;
  RND(17) RND(29) RND(16) RND(24)
  x0 += ks2; x1 += k0 + 2u;
  RND(13) RND(15) RND(26) RND(6)
  x0 += k0;  x1 += k1 + 3u;
  RND(17) RND(29) RND(16) RND(24)
  x0 += k1;  x1 += ks2 + 4u;
  RND(13) RND(15) RND(26) RND(6)
  x0 += ks2; x1 += k0 + 5u;
  o0 = x0; o1 = x1;
#undef RND
#undef ROTL
}

__device__ inline float tf_uniform(uint32_t k0, uint32_t k1, uint32_t idx) {
  uint32_t b1, b2;
  tf2x32(k0, k1, 0u, idx, b1, b2);
  uint32_t bits = b1 ^ b2;
  return __uint_as_float((bits >> 9) | 0x3f800000u) - 1.0f;
}

__device__ inline uint32_t keep_bits(uint32_t e,
                                     uint32_t e00, uint32_t e01,
                                     uint32_t e10, uint32_t e11,
                                     uint32_t e20, uint32_t e21) {
  uint32_t kb = 0u;                              // match reference fp exactly
  if (0.5f + tf_uniform(e00, e01, e) >= 1.0f) kb |= 1u;
  if (0.5f + tf_uniform(e10, e11, e) >= 1.0f) kb |= 2u;
  if (0.5f + tf_uniform(e20, e21, e) >= 1.0f) kb |= 4u;
  return kb;
}

// ---------------- kernels ----------------
// out layout: [n][hop(0..3)][d] float32. Row stride = 256 floats.

// hop0 = concat(user,item). Hop slices 1..3 are fully written by k_spmm_seg.
__global__ __launch_bounds__(256) void k_init(const float4* __restrict__ user,
                                              const float4* __restrict__ item,
                                              float4* __restrict__ out) {
  int idx = blockIdx.x * 256 + threadIdx.x;      // over NTOT*16 float4s
  if (idx >= NTOT * 16) return;
  int n = idx >> 4;
  float4 v = (n < N_USERS) ? user[idx] : item[idx - N_USERS * 16];
  out[(size_t)n * 64 + (idx & 15)] = v;
}

// Fused RNG + row histogram + 512-row-bucket binning. 2048 edges/block,
// 3 phases: LDS bucket-count -> 1 global reservation per touched bucket
// (64B-padded cursors) -> LDS-ranked scattered write of 8B records
//   {x = rloc(9b)<<21 | col(18b)<<3 | kb(3b), y = bits(val*2)}.
__global__ __launch_bounds__(256) void k_hist_bin(const int* __restrict__ rows,
                                                  const int* __restrict__ cols,
                                                  const float* __restrict__ vals,
                                                  uint32_t* __restrict__ cnt,
                                                  uint32_t* __restrict__ gbcur,
                                                  uint2* __restrict__ staging,
                                                  uint32_t e00, uint32_t e01,
                                                  uint32_t e10, uint32_t e11,
                                                  uint32_t e20, uint32_t e21) {
  __shared__ uint32_t bcnt[NBUCK], bbase[NBUCK];
  int t = threadIdx.x;
  int ebase = blockIdx.x * (HB_ITERS * 256);
  for (int b = t; b < NBUCK; b += 256) bcnt[b] = 0u;
  __syncthreads();

  uint32_t srow[HB_ITERS], scol[HB_ITERS], sval[HB_ITERS];
  // phase A: RNG + row histogram + LDS bucket counts
#pragma unroll
  for (int it = 0; it < HB_ITERS; ++it) {
    int e = ebase + it * 256 + t;
    bool valid = (e < NNZ);
    uint32_t kb = valid ? keep_bits((uint32_t)e, e00, e01, e10, e11, e20, e21) : 0u;
    uint32_t row = 0, colkb = 0, v2b = 0;
    if (kb) {
      row = (uint32_t)rows[e];
      colkb = ((uint32_t)cols[e] << 3) | kb;
      v2b = __float_as_uint(vals[e] * 2.0f);     // 1/(1-0.5) = 2
      atomicAdd(&cnt[row], 1u);
      atomicAdd(&bcnt[row >> 9], 1u);
    }
    srow[it] = row; scol[it] = colkb; sval[it] = v2b;
  }
  __syncthreads();
  // phase B: reserve per-bucket global space; reset bcnt for ranking
  for (int b = t; b < NBUCK; b += 256) {
    uint32_t c = bcnt[b];
    bbase[b] = c ? atomicAdd(&gbcur[b * 16], c) : 0u;
    bcnt[b] = 0u;
  }
  __syncthreads();
  // phase C: LDS-ranked write
#pragma unroll
  for (int it = 0; it < HB_ITERS; ++it) {
    uint32_t colkb = scol[it];
    if (colkb & 7u) {
      uint32_t row = srow[it];
      uint32_t b = row >> 9;
      uint32_t rank = atomicAdd(&bcnt[b], 1u);
      staging[(size_t)b * BCAP + bbase[b] + rank] =
          make_uint2(((row & 511u) << 21) | colkb, sval[it]);
    }
  }
}

// block-level exclusive scan (256-wide) + block totals
__global__ __launch_bounds__(256) void k_scan1(const uint32_t* __restrict__ cnt,
                                               uint32_t* __restrict__ strt,
                                               uint32_t* __restrict__ part) {
  __shared__ uint32_t s[256];
  int t = threadIdx.x;
  int i = blockIdx.x * 256 + t;
  uint32_t x = (i < NTOT) ? cnt[i] : 0u;
  s[t] = x; __syncthreads();
  for (int off = 1; off < 256; off <<= 1) {
    uint32_t y = (t >= off) ? s[t - off] : 0u;
    __syncthreads();
    s[t] += y;
    __syncthreads();
  }
  if (i < NTOT) strt[i] = s[t] - x;              // exclusive
  if (t == 255) part[blockIdx.x] = s[255];       // block total
}

// exclusive scan of the 587 block totals (single block)
__global__ __launch_bounds__(1024) void k_scan2(uint32_t* __restrict__ part) {
  __shared__ uint32_t s[1024];
  int t = threadIdx.x;
  uint32_t x = (t < NBLK_SCAN) ? part[t] : 0u;
  s[t] = x; __syncthreads();
  for (int off = 1; off < 1024; off <<= 1) {
    uint32_t y = (t >= off) ? s[t - off] : 0u;
    __syncthreads();
    s[t] += y;
    __syncthreads();
  }
  if (t < NBLK_SCAN) part[t] = s[t] - x;         // exclusive
}

// add block offsets; init per-row scatter cursors (cursors used by fallback)
__global__ __launch_bounds__(256) void k_scan3(uint32_t* __restrict__ strt,
                                               const uint32_t* __restrict__ part,
                                               uint32_t* __restrict__ cur) {
  int i = blockIdx.x * 256 + threadIdx.x;
  if (i >= NTOT) return;
  uint32_t v = strt[i] + part[i >> 8];
  strt[i] = v;
  cur[i] = v;
}

// LDS counting-sort: one block per 512-row bucket. Sequential staging read,
// LDS placement at final position, fully COALESCED write to rec.
__global__ __launch_bounds__(1024) void k_sort(const uint2* __restrict__ staging,
                                               const uint32_t* __restrict__ gbcur,
                                               const uint32_t* __restrict__ strt,
                                               uint2* __restrict__ rec) {
  __shared__ uint2 lbuf[BCAP];
  __shared__ uint32_t lcur[512];
  int t = threadIdx.x;
  int b = blockIdx.x;
  int base_row = b << 9;
  uint32_t base_pos = strt[base_row];
  uint32_t n = gbcur[b * 16];
  if (t < 512) {
    int r = base_row + t;
    lcur[t] = (r < NTOT) ? (strt[r] - base_pos) : 0u;
  }
  __syncthreads();
  const uint2* sg = staging + (size_t)b * BCAP;
  for (uint32_t i = t; i < n; i += 1024) {
    uint2 v = sg[i];
    uint32_t rloc = v.x >> 21;
    uint32_t p = atomicAdd(&lcur[rloc], 1u);
    lbuf[p] = make_uint2(v.x & 0x1FFFFFu, v.y);
  }
  __syncthreads();
  for (uint32_t p = t; p < n; p += 1024) {
    rec[base_pos + p] = lbuf[p];
  }
}

// ---- fallback (small ws): round-7 style hist + single-pass scatter ----
__global__ __launch_bounds__(256) void k_hist_fb(const int* __restrict__ rows,
                                                 uint32_t* __restrict__ cnt,
                                                 uint8_t* __restrict__ kbits,
                                                 uint32_t e00, uint32_t e01,
                                                 uint32_t e10, uint32_t e11,
                                                 uint32_t e20, uint32_t e21) {
  int e = blockIdx.x * 256 + threadIdx.x;
  if (e >= NNZ) return;
  uint32_t kb = keep_bits((uint32_t)e, e00, e01, e10, e11, e20, e21);
  int row = rows[e];
  uint32_t oct = (uint32_t)row / OCT_ROWS;
  kbits[e] = (uint8_t)(kb | (oct << 4));
  if (kb) atomicAdd(&cnt[row], 1u);
}

__global__ __launch_bounds__(256) void k_scatter_fb(const float* __restrict__ vals,
                                                    const int* __restrict__ rows,
                                                    const int* __restrict__ cols,
                                                    const uint8_t* __restrict__ kbits,
                                                    uint32_t* __restrict__ cur,
                                                    uint2* __restrict__ rec) {
  int e = (blockIdx.x >> 3) * 256 + threadIdx.x;
  if (e >= NNZ) return;
  uint32_t oct = (uint32_t)(blockIdx.x & 7);
  uint32_t kbv = kbits[e];
  if ((kbv >> 4) != oct) return;
  uint32_t kb = kbv & 7u;
  if (!kb) return;
  uint32_t j = atomicAdd(&cur[rows[e]], 1u);
  rec[j] = make_uint2(((uint32_t)cols[e] << 3) | kb,
                      __float_as_uint(vals[e] * 2.0f));
}

// segmented SpMM (proven round-6 version): one WAVE per 4 rows;
// 16 lanes x float4 per row; 4 independent row-chains x unroll-4 = up to
// 16 outstanding gathers/wave. Dropped-this-hop edges gather row 0 (L1-hot)
// with v=0 (branchless). rec loads cached. Fused message dropout.
__global__ __launch_bounds__(256) void k_spmm_seg(const uint32_t* __restrict__ strt,
                                                  const uint32_t* __restrict__ cnt,
                                                  const uint2* __restrict__ rec,
                                                  float* __restrict__ out,
                                                  int hop, uint32_t km0, uint32_t km1) {
  int wave = (blockIdx.x * 256 + threadIdx.x) >> 6;
  int lane = threadIdx.x & 63;
  int g = lane >> 4;                 // row subgroup 0..3
  int q = lane & 15;                 // float4 chunk 0..15
  int row = wave * 4 + g;
  if (row >= NTOT) return;
  uint32_t s = strt[row];
  uint32_t e = s + cnt[row];
  const uint32_t mask = 1u << hop;
  // src row c, float4 chunk q lives at float4 index c*64 + hop*16 + q
  const float4* srcb = (const float4*)out + (size_t)hop * 16 + q;
  float4 a0 = {0.f,0.f,0.f,0.f}, a1 = a0, a2 = a0, a3 = a0;
  uint32_t j = s;
  for (; j + 4 <= e; j += 4) {
    uint2 r0 = rec[j], r1 = rec[j + 1], r2 = rec[j + 2], r3 = rec[j + 3];
    bool k0 = (r0.x & mask) != 0u, k1 = (r1.x & mask) != 0u;
    bool k2 = (r2.x & mask) != 0u, k3 = (r3.x & mask) != 0u;
    size_t c0 = k0 ? (size_t)(r0.x >> 3) * 64 : 0;
    size_t c1 = k1 ? (size_t)(r1.x >> 3) * 64 : 0;
    size_t c2 = k2 ? (size_t)(r2.x >> 3) * 64 : 0;
    size_t c3 = k3 ? (size_t)(r3.x >> 3) * 64 : 0;
    float4 s0 = srcb[c0], s1 = srcb[c1], s2 = srcb[c2], s3 = srcb[c3];
    float v0 = k0 ? __uint_as_float(r0.y) : 0.f;
    float v1 = k1 ? __uint_as_float(r1.y) : 0.f;
    float v2 = k2 ? __uint_as_float(r2.y) : 0.f;
    float v3 = k3 ? __uint_as_float(r3.y) : 0.f;
    a0.x += v0 * s0.x; a0.y += v0 * s0.y; a0.z += v0 * s0.z; a0.w += v0 * s0.w;
    a1.x += v1 * s1.x; a1.y += v1 * s1.y; a1.z += v1 * s1.z; a1.w += v1 * s1.w;
    a2.x += v2 * s2.x; a2.y += v2 * s2.y; a2.z += v2 * s2.z; a2.w += v2 * s2.w;
    a3.x += v3 * s3.x; a3.y += v3 * s3.y; a3.z += v3 * s3.z; a3.w += v3 * s3.w;
  }
  for (; j < e; ++j) {
    uint2 r = rec[j];
    if (r.x & mask) {
      float v = __uint_as_float(r.y);
      float4 sv = srcb[(size_t)(r.x >> 3) * 64];
      a0.x += v * sv.x; a0.y += v * sv.y; a0.z += v * sv.z; a0.w += v * sv.w;
    }
  }
  float4 acc;
  acc.x = (a0.x + a1.x) + (a2.x + a3.x);
  acc.y = (a0.y + a1.y) + (a2.y + a3.y);
  acc.z = (a0.z + a1.z) + (a2.z + a3.z);
  acc.w = (a0.w + a1.w) + (a2.w + a3.w);
  // message dropout (inverted, keep iff u < 0.9), flat index over (NTOT, DIM)
  uint32_t base = (uint32_t)(row * 64 + q * 4);
  float u0 = tf_uniform(km0, km1, base + 0u);
  float u1 = tf_uniform(km0, km1, base + 1u);
  float u2 = tf_uniform(km0, km1, base + 2u);
  float u3 = tf_uniform(km0, km1, base + 3u);
  const float sc = (float)(1.0 / 0.9);
  acc.x = (u0 < 0.9f) ? acc.x * sc : 0.0f;
  acc.y = (u1 < 0.9f) ? acc.y * sc : 0.0f;
  acc.z = (u2 < 0.9f) ? acc.z * sc : 0.0f;
  acc.w = (u3 < 0.9f) ? acc.w * sc : 0.0f;
  ((float4*)(out + ((size_t)row * 4 + hop + 1) * 64))[q] = acc;
}

// ---------------- launch ----------------
extern "C" void kernel_launch(void* const* d_in, const int* in_sizes, int n_in,
                              void* d_out, int out_size, void* d_ws, size_t ws_size,
                              hipStream_t stream) {
  const float* user = (const float*)d_in[0];
  const float* item = (const float*)d_in[1];
  const float* vals = (const float*)d_in[2];
  const int*   rows = (const int*)d_in[3];
  const int*   cols = (const int*)d_in[4];
  float* out = (float*)d_out;

  // workspace layout (big path ~32.8 MB; fallback ~19.8 MB)
  char* w = (char*)d_ws;
  uint32_t* cnt     = (uint32_t*)(w);                 // 600,000 B
  uint32_t* gbcur   = (uint32_t*)(w + 600000);        // 18,752 B (293 x 64B)
  uint32_t* strt    = (uint32_t*)(w + 618752);        // 600,000 B
  uint32_t* cur     = (uint32_t*)(w + 1218752);       // 600,000 B (fallback)
  uint32_t* part    = (uint32_t*)(w + 1818752);       // 4,096 B
  uint2*    rec     = (uint2*)   (w + 1822848);       // 16,000,000 B
  uint2*    staging = (uint2*)   (w + 17822848);      // 15,001,600 B
  uint8_t*  kbits   = (uint8_t*) (w + 17822848);      // fallback alias: 2 MB
  const size_t NEEDED = 17822848 + (size_t)NBUCK * BCAP * 8;
  bool big = ws_size >= NEEDED;

  // host-side key schedule: key(42) -> per-hop (dkey, ke, km)
  uint32_t k0 = 0u, k1 = 42u;
  uint32_t ke[NHOPS][2], km[NHOPS][2];
  for (int h = 0; h < NHOPS; ++h) {
    uint32_t nk0, nk1;
    tf2x32(k0, k1, 0u, 0u, nk0, nk1);
    tf2x32(k0, k1, 0u, 1u, ke[h][0], ke[h][1]);
    tf2x32(k0, k1, 0u, 2u, km[h][0], km[h][1]);
    k0 = nk0; k1 = nk1;
  }

  hipMemsetAsync(cnt, 0, 618752, stream);   // cnt + gbcur
  if (big) {
    k_hist_bin<<<(NNZ + HB_ITERS * 256 - 1) / (HB_ITERS * 256), 256, 0, stream>>>(
        rows, cols, vals, cnt, gbcur, staging,
        ke[0][0], ke[0][1], ke[1][0], ke[1][1], ke[2][0], ke[2][1]);
  } else {
    k_hist_fb<<<(NNZ + 255) / 256, 256, 0, stream>>>(
        rows, cnt, kbits,
        ke[0][0], ke[0][1], ke[1][0], ke[1][1], ke[2][0], ke[2][1]);
  }
  k_scan1<<<NBLK_SCAN, 256, 0, stream>>>(cnt, strt, part);
  k_scan2<<<1, 1024, 0, stream>>>(part);
  k_scan3<<<NBLK_SCAN, 256, 0, stream>>>(strt, part, cur);
  if (big) {
    k_sort<<<NBUCK, 1024, 0, stream>>>(staging, gbcur, strt, rec);
  } else {
    k_scatter_fb<<<NOCT * ((NNZ + 255) / 256), 256, 0, stream>>>(
        vals, rows, cols, kbits, cur, rec);
  }
  k_init<<<(NTOT * 16 + 255) / 256, 256, 0, stream>>>(
      (const float4*)user, (const float4*)item, (float4*)out);

  for (int h = 0; h < NHOPS; ++h) {
    k_spmm_seg<<<((NTOT + 3) / 4 * 64 + 255) / 256, 256, 0, stream>>>(
        strt, cnt, rec, out, h, km[h][0], km[h][1]);
  }
}

// Round 12
// 238.747 us; speedup vs baseline: 2.7392x; 1.2118x over previous
//
#include <hip/hip_runtime.h>
#include <stdint.h>

#define N_USERS 100000
#define N_ITEMS 50000
#define NTOT    150000
#define DIM     64
#define NNZ     2000000
#define NHOPS   3
#define NBLK_SCAN ((NTOT + 255) / 256)   // 587 (fallback)
#define NOCT    8
#define OCT_ROWS (NTOT / NOCT)           // 18750 (fallback)
#define NBUCK   293                      // buckets of 512 rows (row>>9)
#define BCAP    6400                     // mean 5973 + ~5.5 sigma
#define HB_EDGES 4096                    // edges per hist block

// ---------------- Threefry-2x32, 20 rounds (JAX-compatible) ----------------
__host__ __device__ inline void tf2x32(uint32_t k0, uint32_t k1,
                                       uint32_t x0, uint32_t x1,
                                       uint32_t& o0, uint32_t& o1) {
  uint32_t ks2 = k0 ^ k1 ^ 0x1BD11BDAu;
  x0 += k0; x1 += k1;
#define ROTL(x,r) (((x) << (r)) | ((x) >> (32 - (r))))
#define RND(r) { x0 += x1; x1 = ROTL(x1, r); x1 ^= x0; }
  RND(13) RND(15) RND(26) RND(6)
  x0 += k1;  x1 += ks2 + 1u;
  RND(17) RND(29) RND(16) RND(24)
  x0 += ks2; x1 += k0 + 2u;
  RND(13) RND(15) RND(26) RND(6)
  x0 += k0;  x1 += k1 + 3u;
  RND(17) RND(29) RND(16) RND(24)
  x0 += k1;  x1 += ks2 + 4u;
  RND(13) RND(15) RND(26) RND(6)
  x0 += ks2; x1 += k0 + 5u;
  o0 = x0; o1 = x1;
#undef RND
#undef ROTL
}

__device__ inline float tf_uniform(uint32_t k0, uint32_t k1, uint32_t idx) {
  uint32_t b1, b2;
  tf2x32(k0, k1, 0u, idx, b1, b2);
  uint32_t bits = b1 ^ b2;
  return __uint_as_float((bits >> 9) | 0x3f800000u) - 1.0f;
}

__device__ inline uint32_t keep_bits(uint32_t e,
                                     uint32_t e00, uint32_t e01,
                                     uint32_t e10, uint32_t e11,
                                     uint32_t e20, uint32_t e21) {
  uint32_t kb = 0u;                              // match reference fp exactly
  if (0.5f + tf_uniform(e00, e01, e) >= 1.0f) kb |= 1u;
  if (0.5f + tf_uniform(e10, e11, e) >= 1.0f) kb |= 2u;
  if (0.5f + tf_uniform(e20, e21, e) >= 1.0f) kb |= 4u;
  return kb;
}

// ---------------- kernels ----------------
// out layout: [n][hop(0..3)][d] float32. Row stride = 256 floats.

// hop0 = concat(user,item). Hop slices 1..3 are fully written by k_spmm_seg.
__global__ __launch_bounds__(256) void k_init(const float4* __restrict__ user,
                                              const float4* __restrict__ item,
                                              float4* __restrict__ out) {
  int idx = blockIdx.x * 256 + threadIdx.x;      // over NTOT*16 float4s
  if (idx >= NTOT * 16) return;
  int n = idx >> 4;
  float4 v = (n < N_USERS) ? user[idx] : item[idx - N_USERS * 16];
  out[(size_t)n * 64 + (idx & 15)] = v;
}

// Fused RNG + 512-row-bucket binning. 4096 edges/block, kb cached in LDS.
// NO per-row atomics (row hist derived later in k_sort). 8B records:
//   {x = rloc(9b)<<21 | col(18b)<<3 | kb(3b), y = bits(val*2)}
__global__ __launch_bounds__(256) void k_hist_bin(const int* __restrict__ rows,
                                                  const int* __restrict__ cols,
                                                  const float* __restrict__ vals,
                                                  uint32_t* __restrict__ gbcur,
                                                  uint2* __restrict__ staging,
                                                  uint32_t e00, uint32_t e01,
                                                  uint32_t e10, uint32_t e11,
                                                  uint32_t e20, uint32_t e21) {
  __shared__ uint32_t bcnt[NBUCK], bbase[NBUCK];
  __shared__ uint8_t lkb[HB_EDGES];
  int t = threadIdx.x;
  int ebase = blockIdx.x * HB_EDGES;
  for (int b = t; b < NBUCK; b += 256) bcnt[b] = 0u;
  __syncthreads();
  // phase A: RNG + LDS bucket counts (kb cached)
  for (int it = 0; it < HB_EDGES / 256; ++it) {
    int e = ebase + it * 256 + t;
    uint32_t kb = (e < NNZ) ? keep_bits((uint32_t)e, e00, e01, e10, e11, e20, e21) : 0u;
    lkb[it * 256 + t] = (uint8_t)kb;
    if (kb) atomicAdd(&bcnt[(uint32_t)rows[e] >> 9], 1u);
  }
  __syncthreads();
  // phase B: one global reservation per touched bucket (64B-padded cursors)
  for (int b = t; b < NBUCK; b += 256) {
    uint32_t c = bcnt[b];
    bbase[b] = c ? atomicAdd(&gbcur[b * 16], c) : 0u;
    bcnt[b] = 0u;
  }
  __syncthreads();
  // phase C: LDS-ranked write (runs of ~12 records per bucket per block)
  for (int it = 0; it < HB_EDGES / 256; ++it) {
    int e = ebase + it * 256 + t;
    uint32_t kb = (e < NNZ) ? (uint32_t)lkb[it * 256 + t] : 0u;
    if (kb) {
      uint32_t row = (uint32_t)rows[e];
      uint32_t b = row >> 9;
      uint32_t rank = atomicAdd(&bcnt[b], 1u);
      staging[(size_t)b * BCAP + bbase[b] + rank] =
          make_uint2(((row & 511u) << 21) | ((uint32_t)cols[e] << 3) | kb,
                     __float_as_uint(vals[e] * 2.0f));   // 1/(1-0.5) = 2
    }
  }
}

// exclusive scan of the 293 bucket totals (single block)
__global__ __launch_bounds__(512) void k_bscan(const uint32_t* __restrict__ gbcur,
                                               uint32_t* __restrict__ bstart) {
  __shared__ uint32_t s[512];
  int t = threadIdx.x;
  uint32_t x = (t < NBUCK) ? gbcur[t * 16] : 0u;
  s[t] = x; __syncthreads();
  for (int off = 1; off < 512; off <<= 1) {
    uint32_t y = (t >= off) ? s[t - off] : 0u;
    __syncthreads();
    s[t] += y;
    __syncthreads();
  }
  if (t < NBUCK) bstart[t] = s[t] - x;           // exclusive
}

// LDS counting-sort per bucket: staging->LDS, per-row count + local scan
// (writes strt/cnt for its 512 rows -- replaces the global row scans),
// rank into LDS out-buffer, fully COALESCED write to rec.
__global__ __launch_bounds__(1024) void k_sort(const uint2* __restrict__ staging,
                                               const uint32_t* __restrict__ gbcur,
                                               const uint32_t* __restrict__ bstart,
                                               uint2* __restrict__ rec,
                                               uint32_t* __restrict__ strt,
                                               uint32_t* __restrict__ cnt) {
  __shared__ uint2 lraw[BCAP];       // 51.2 KB
  __shared__ uint2 lout[BCAP];       // 51.2 KB
  __shared__ uint32_t lcnt[512], lcur[512];
  int t = threadIdx.x;
  int b = blockIdx.x;
  int base_row = b << 9;
  uint32_t n = gbcur[b * 16];
  uint32_t base_pos = bstart[b];
  if (t < 512) lcnt[t] = 0u;
  __syncthreads();
  const uint2* sg = staging + (size_t)b * BCAP;
  for (uint32_t i = t; i < n; i += 1024) {
    uint2 v = sg[i];
    lraw[i] = v;
    atomicAdd(&lcnt[v.x >> 21], 1u);
  }
  __syncthreads();
  uint32_t myc = (t < 512) ? lcnt[t] : 0u;
  for (int off = 1; off < 512; off <<= 1) {      // inclusive scan over 512
    uint32_t y = (t < 512 && t >= off) ? lcnt[t - off] : 0u;
    __syncthreads();
    if (t < 512) lcnt[t] += y;
    __syncthreads();
  }
  if (t < 512) {
    uint32_t excl = lcnt[t] - myc;
    lcur[t] = excl;
    int r = base_row + t;
    if (r < NTOT) { strt[r] = base_pos + excl; cnt[r] = myc; }
  }
  __syncthreads();
  for (uint32_t i = t; i < n; i += 1024) {
    uint2 v = lraw[i];
    uint32_t p = atomicAdd(&lcur[v.x >> 21], 1u);
    lout[p] = make_uint2(v.x & 0x1FFFFFu, v.y);
  }
  __syncthreads();
  for (uint32_t i = t; i < n; i += 1024) rec[base_pos + i] = lout[i];
}

// ---- fallback (small ws): round-7 style pipeline ----
__global__ __launch_bounds__(256) void k_hist_fb(const int* __restrict__ rows,
                                                 uint32_t* __restrict__ cnt,
                                                 uint8_t* __restrict__ kbits,
                                                 uint32_t e00, uint32_t e01,
                                                 uint32_t e10, uint32_t e11,
                                                 uint32_t e20, uint32_t e21) {
  int e = blockIdx.x * 256 + threadIdx.x;
  if (e >= NNZ) return;
  uint32_t kb = keep_bits((uint32_t)e, e00, e01, e10, e11, e20, e21);
  int row = rows[e];
  uint32_t oct = (uint32_t)row / OCT_ROWS;
  kbits[e] = (uint8_t)(kb | (oct << 4));
  if (kb) atomicAdd(&cnt[row], 1u);
}

__global__ __launch_bounds__(256) void k_scan1(const uint32_t* __restrict__ cnt,
                                               uint32_t* __restrict__ strt,
                                               uint32_t* __restrict__ part) {
  __shared__ uint32_t s[256];
  int t = threadIdx.x;
  int i = blockIdx.x * 256 + t;
  uint32_t x = (i < NTOT) ? cnt[i] : 0u;
  s[t] = x; __syncthreads();
  for (int off = 1; off < 256; off <<= 1) {
    uint32_t y = (t >= off) ? s[t - off] : 0u;
    __syncthreads();
    s[t] += y;
    __syncthreads();
  }
  if (i < NTOT) strt[i] = s[t] - x;
  if (t == 255) part[blockIdx.x] = s[255];
}

__global__ __launch_bounds__(1024) void k_scan2(uint32_t* __restrict__ part) {
  __shared__ uint32_t s[1024];
  int t = threadIdx.x;
  uint32_t x = (t < NBLK_SCAN) ? part[t] : 0u;
  s[t] = x; __syncthreads();
  for (int off = 1; off < 1024; off <<= 1) {
    uint32_t y = (t >= off) ? s[t - off] : 0u;
    __syncthreads();
    s[t] += y;
    __syncthreads();
  }
  if (t < NBLK_SCAN) part[t] = s[t] - x;
}

__global__ __launch_bounds__(256) void k_scan3(uint32_t* __restrict__ strt,
                                               const uint32_t* __restrict__ part,
                                               uint32_t* __restrict__ cur) {
  int i = blockIdx.x * 256 + threadIdx.x;
  if (i >= NTOT) return;
  uint32_t v = strt[i] + part[i >> 8];
  strt[i] = v;
  cur[i] = v;
}

__global__ __launch_bounds__(256) void k_scatter_fb(const float* __restrict__ vals,
                                                    const int* __restrict__ rows,
                                                    const int* __restrict__ cols,
                                                    const uint8_t* __restrict__ kbits,
                                                    uint32_t* __restrict__ cur,
                                                    uint2* __restrict__ rec) {
  int e = (blockIdx.x >> 3) * 256 + threadIdx.x;
  if (e >= NNZ) return;
  uint32_t oct = (uint32_t)(blockIdx.x & 7);
  uint32_t kbv = kbits[e];
  if ((kbv >> 4) != oct) return;
  uint32_t kb = kbv & 7u;
  if (!kb) return;
  uint32_t j = atomicAdd(&cur[rows[e]], 1u);
  rec[j] = make_uint2(((uint32_t)cols[e] << 3) | kb,
                      __float_as_uint(vals[e] * 2.0f));
}

// segmented SpMM (proven round-6 version): one WAVE per 4 rows;
// 16 lanes x float4 per row; 4 independent row-chains x unroll-4 = up to
// 16 outstanding gathers/wave. Dropped-this-hop edges gather row 0 (L1-hot)
// with v=0 (branchless). rec loads cached. Fused message dropout.
__global__ __launch_bounds__(256) void k_spmm_seg(const uint32_t* __restrict__ strt,
                                                  const uint32_t* __restrict__ cnt,
                                                  const uint2* __restrict__ rec,
                                                  float* __restrict__ out,
                                                  int hop, uint32_t km0, uint32_t km1) {
  int wave = (blockIdx.x * 256 + threadIdx.x) >> 6;
  int lane = threadIdx.x & 63;
  int g = lane >> 4;                 // row subgroup 0..3
  int q = lane & 15;                 // float4 chunk 0..15
  int row = wave * 4 + g;
  if (row >= NTOT) return;
  uint32_t s = strt[row];
  uint32_t e = s + cnt[row];
  const uint32_t mask = 1u << hop;
  // src row c, float4 chunk q lives at float4 index c*64 + hop*16 + q
  const float4* srcb = (const float4*)out + (size_t)hop * 16 + q;
  float4 a0 = {0.f,0.f,0.f,0.f}, a1 = a0, a2 = a0, a3 = a0;
  uint32_t j = s;
  for (; j + 4 <= e; j += 4) {
    uint2 r0 = rec[j], r1 = rec[j + 1], r2 = rec[j + 2], r3 = rec[j + 3];
    bool k0 = (r0.x & mask) != 0u, k1 = (r1.x & mask) != 0u;
    bool k2 = (r2.x & mask) != 0u, k3 = (r3.x & mask) != 0u;
    size_t c0 = k0 ? (size_t)(r0.x >> 3) * 64 : 0;
    size_t c1 = k1 ? (size_t)(r1.x >> 3) * 64 : 0;
    size_t c2 = k2 ? (size_t)(r2.x >> 3) * 64 : 0;
    size_t c3 = k3 ? (size_t)(r3.x >> 3) * 64 : 0;
    float4 s0 = srcb[c0], s1 = srcb[c1], s2 = srcb[c2], s3 = srcb[c3];
    float v0 = k0 ? __uint_as_float(r0.y) : 0.f;
    float v1 = k1 ? __uint_as_float(r1.y) : 0.f;
    float v2 = k2 ? __uint_as_float(r2.y) : 0.f;
    float v3 = k3 ? __uint_as_float(r3.y) : 0.f;
    a0.x += v0 * s0.x; a0.y += v0 * s0.y; a0.z += v0 * s0.z; a0.w += v0 * s0.w;
    a1.x += v1 * s1.x; a1.y += v1 * s1.y; a1.z += v1 * s1.z; a1.w += v1 * s1.w;
    a2.x += v2 * s2.x; a2.y += v2 * s2.y; a2.z += v2 * s2.z; a2.w += v2 * s2.w;
    a3.x += v3 * s3.x; a3.y += v3 * s3.y; a3.z += v3 * s3.z; a3.w += v3 * s3.w;
  }
  for (; j < e; ++j) {
    uint2 r = rec[j];
    if (r.x & mask) {
      float v = __uint_as_float(r.y);
      float4 sv = srcb[(size_t)(r.x >> 3) * 64];
      a0.x += v * sv.x; a0.y += v * sv.y; a0.z += v * sv.z; a0.w += v * sv.w;
    }
  }
  float4 acc;
  acc.x = (a0.x + a1.x) + (a2.x + a3.x);
  acc.y = (a0.y + a1.y) + (a2.y + a3.y);
  acc.z = (a0.z + a1.z) + (a2.z + a3.z);
  acc.w = (a0.w + a1.w) + (a2.w + a3.w);
  // message dropout (inverted, keep iff u < 0.9), flat index over (NTOT, DIM)
  uint32_t base = (uint32_t)(row * 64 + q * 4);
  float u0 = tf_uniform(km0, km1, base + 0u);
  float u1 = tf_uniform(km0, km1, base + 1u);
  float u2 = tf_uniform(km0, km1, base + 2u);
  float u3 = tf_uniform(km0, km1, base + 3u);
  const float sc = (float)(1.0 / 0.9);
  acc.x = (u0 < 0.9f) ? acc.x * sc : 0.0f;
  acc.y = (u1 < 0.9f) ? acc.y * sc : 0.0f;
  acc.z = (u2 < 0.9f) ? acc.z * sc : 0.0f;
  acc.w = (u3 < 0.9f) ? acc.w * sc : 0.0f;
  ((float4*)(out + ((size_t)row * 4 + hop + 1) * 64))[q] = acc;
}

// ---------------- launch ----------------
extern "C" void kernel_launch(void* const* d_in, const int* in_sizes, int n_in,
                              void* d_out, int out_size, void* d_ws, size_t ws_size,
                              hipStream_t stream) {
  const float* user = (const float*)d_in[0];
  const float* item = (const float*)d_in[1];
  const float* vals = (const float*)d_in[2];
  const int*   rows = (const int*)d_in[3];
  const int*   cols = (const int*)d_in[4];
  float* out = (float*)d_out;

  // workspace layout (big path ~32.8 MB; fallback ~19.8 MB)
  char* w = (char*)d_ws;
  uint32_t* gbcur   = (uint32_t*)(w);                 // 18,752 B (293 x 64B)
  uint32_t* bstart  = (uint32_t*)(w + 18752);         // 4,096 B
  uint32_t* strt    = (uint32_t*)(w + 22848);         // 600,000 B
  uint32_t* cnt     = (uint32_t*)(w + 622848);        // 600,000 B
  uint32_t* cur     = (uint32_t*)(w + 1222848);       // 600,000 B (fallback)
  uint32_t* part    = (uint32_t*)(w + 1822848);       // 4,096 B (fallback)
  uint2*    rec     = (uint2*)   (w + 1826944);       // 16,000,000 B
  uint2*    staging = (uint2*)   (w + 17826944);      // 15,001,600 B
  uint8_t*  kbits   = (uint8_t*) (w + 17826944);      // fallback alias: 2 MB
  const size_t NEEDED = 17826944 + (size_t)NBUCK * BCAP * 8;
  bool big = ws_size >= NEEDED;

  // host-side key schedule: key(42) -> per-hop (dkey, ke, km)
  uint32_t k0 = 0u, k1 = 42u;
  uint32_t ke[NHOPS][2], km[NHOPS][2];
  for (int h = 0; h < NHOPS; ++h) {
    uint32_t nk0, nk1;
    tf2x32(k0, k1, 0u, 0u, nk0, nk1);
    tf2x32(k0, k1, 0u, 1u, ke[h][0], ke[h][1]);
    tf2x32(k0, k1, 0u, 2u, km[h][0], km[h][1]);
    k0 = nk0; k1 = nk1;
  }

  if (big) {
    hipMemsetAsync(gbcur, 0, 18752, stream);
    k_hist_bin<<<(NNZ + HB_EDGES - 1) / HB_EDGES, 256, 0, stream>>>(
        rows, cols, vals, gbcur, staging,
        ke[0][0], ke[0][1], ke[1][0], ke[1][1], ke[2][0], ke[2][1]);
    k_bscan<<<1, 512, 0, stream>>>(gbcur, bstart);
    k_sort<<<NBUCK, 1024, 0, stream>>>(staging, gbcur, bstart, rec, strt, cnt);
  } else {
    hipMemsetAsync(cnt, 0, 600000, stream);
    k_hist_fb<<<(NNZ + 255) / 256, 256, 0, stream>>>(
        rows, cnt, kbits,
        ke[0][0], ke[0][1], ke[1][0], ke[1][1], ke[2][0], ke[2][1]);
    k_scan1<<<NBLK_SCAN, 256, 0, stream>>>(cnt, strt, part);
    k_scan2<<<1, 1024, 0, stream>>>(part);
    k_scan3<<<NBLK_SCAN, 256, 0, stream>>>(strt, part, cur);
    k_scatter_fb<<<NOCT * ((NNZ + 255) / 256), 256, 0, stream>>>(
        vals, rows, cols, kbits, cur, rec);
  }
  k_init<<<(NTOT * 16 + 255) / 256, 256, 0, stream>>>(
      (const float4*)user, (const float4*)item, (float4*)out);

  for (int h = 0; h < NHOPS; ++h) {
    k_spmm_seg<<<((NTOT + 3) / 4 * 64 + 255) / 256, 256, 0, stream>>>(
        strt, cnt, rec, out, h, km[h][0], km[h][1]);
  }
}